// Round 13
// baseline (141.656 us; speedup 1.0000x reference)
//
#include <hip/hip_runtime.h>

// Causal quadratic linear attention, chunked-scan formulation.
//   (q.k)^2 = sum_{i,j} q_i q_j k_i k_j   (256 ordered-pair features, f = 16i+j)
// CHUNK=128, NCHUNK=32. TWO launches:
// p01f : per (h,c) block (256 x 512): stage K/V in LDS; chunk state G via
//        operand-swapped MFMA (frag-native coalesced write); intra-chunk
//        causal part from the staged LDS tiles -> fp32 O/Z partials in Og.
//        LAST block of each head (device atomic, no spin) then scans that
//        head's G into Hb in LDS-IMAGE order (decode+swizzle on write side).
// p3s  : per (h,c,qh) block (512 x 256, 2/CU): pure-streaming 40KB Hb->LDS
//        copy (zero decode), 45 MFMAs/wave state apply, O += state RMW.
// LDS: power-of-2 row strides + XOR swizzle (byte ^= (row&7)<<4).

#define SEQN 4096
#define NHEAD 8
#define DKEY 16
#define DVAL 64
#define CHUNK 128
#define NCHUNK 32
#define ALPHA 0.03125f

typedef float f32x4 __attribute__((ext_vector_type(4)));
typedef __bf16 bf16x4 __attribute__((ext_vector_type(4)));
typedef __bf16 bf16x8 __attribute__((ext_vector_type(8)));
typedef unsigned long long u64;
typedef u64 u64x2 __attribute__((ext_vector_type(2)));

#define SW512(row, colb) (((row) << 9) + ((colb) ^ (((row) & 7) << 4)))
#define SW256(row, colb) (((row) << 8) + ((colb) ^ (((row) & 7) << 4)))

__device__ inline float bf2f(__bf16 x) {
    unsigned short u = __builtin_bit_cast(unsigned short, x);
    unsigned int v = ((unsigned int)u) << 16;
    return __builtin_bit_cast(float, v);
}

// ---------------- Phase 01 fused: stage + chunk state + intra + per-head scan ----------------
// grid 256 = (h = bid&7, c = bid>>3), 512 thr (8 waves; wave w: queries 16w..+15).
__global__ __launch_bounds__(512, 1)
void p01_fused(const float* __restrict__ Kg, const float* __restrict__ Vg,
               const float* __restrict__ Qg, __bf16* __restrict__ G,
               __bf16* __restrict__ Hb, unsigned* __restrict__ cnt,
               float* __restrict__ Og)
{
    __shared__ __align__(128) unsigned char Vt2[80 * 256];   // bf16 [80][128], swz (20KB)
    __shared__ __align__(128) unsigned char Ktf[16 * 512];   // f32  [16][128], swz (8KB)
    __shared__ __align__(128) unsigned char Kl[128 * 32];    // bf16 [128][16], swz (4KB)
    __shared__ int isLast;
    const int tid = threadIdx.x;
    const int w = tid >> 6;          // wave 0..7
    const int lane = tid & 63;
    const int r = lane & 15, g = lane >> 4;
    const int bid = blockIdx.x;
    const int h = bid & 7, c = bid >> 3;              // c: 0..31
    const int k0 = c * CHUNK;
    const int qb = k0 + 16 * w;

    // ---- Q row load (issued early, in flight during staging) ----
    float qr[16];
    {
        const float* qp = Qg + ((size_t)h * SEQN + qb + r) * DKEY;
        #pragma unroll
        for (int m = 0; m < 4; ++m) {
            const f32x4 v = *(const f32x4*)(qp + 4 * m);
            qr[4 * m + 0] = v[0]; qr[4 * m + 1] = v[1];
            qr[4 * m + 2] = v[2]; qr[4 * m + 3] = v[3];
        }
    }

    // ---- stage K: Ktf (f32 transposed, swz) + Kl (bf16 row-major, swz) ----
    {
        const int key = tid >> 2, part = tid & 3;
        const float* kp = Kg + ((size_t)h * SEQN + k0 + key) * DKEY + 4 * part;
        const f32x4 a = *(const f32x4*)kp;
        #pragma unroll
        for (int j = 0; j < 4; ++j)
            *(float*)(Ktf + SW512(4 * part + j, key * 4)) = a[j];
        bf16x4 o;
        #pragma unroll
        for (int j = 0; j < 4; ++j) o[j] = (__bf16)a[j];
        *(bf16x4*)(Kl + key * 32 + ((8 * part) ^ ((key & 1) << 4))) = o;
    }
    // ---- stage V rows 0..63 (dim el, cols t, swz) ----
    {
        const int el = tid & 63;
        const int seg = tid >> 6;
        const float* __restrict__ Vh = Vg + (size_t)h * SEQN * DVAL;
        #pragma unroll
        for (int p = 0; p < 2; ++p) {
            const int tb = 8 * (seg + 8 * p);    // 0..120
            bf16x8 v;
            #pragma unroll
            for (int j = 0; j < 8; ++j)
                v[j] = (__bf16)Vh[(size_t)(k0 + tb + j) * DVAL + el];
            *(bf16x8*)(Vt2 + SW256(el, tb * 2)) = v;
        }
    }
    // ---- rows 64..79: ones (row 64) / zeros ----
    {
        const int row = 64 + (tid >> 5);
        const int i = tid & 31;
        const u64 val = (row == 64) ? 0x3F803F803F803F80ULL : 0ULL;
        *(u64*)(Vt2 + SW256(row, 8 * i)) = val;
    }
    __syncthreads();

    // ---- MFMA: G[e][f]; wave w owns f-tiles 2w, 2w+1 (operand-swapped) ----
    {
        f32x4 acc[2][5] = {};
        #pragma unroll
        for (int ks = 0; ks < 4; ++ks) {
            const int t0 = 32 * ks + 8 * g;
            bf16x8 af[5];
            #pragma unroll
            for (int et = 0; et < 5; ++et)
                af[et] = *(const bf16x8*)(Vt2 + SW256(16 * et + r, t0 * 2));
            const f32x4 kra = *(const f32x4*)(Ktf + SW512(r, t0 * 4));
            const f32x4 krb = *(const f32x4*)(Ktf + SW512(r, t0 * 4 + 16));
            #pragma unroll
            for (int fa = 0; fa < 2; ++fa) {
                const int ft = 2 * w + fa;
                const f32x4 kfa = *(const f32x4*)(Ktf + SW512(ft, t0 * 4));
                const f32x4 kfb = *(const f32x4*)(Ktf + SW512(ft, t0 * 4 + 16));
                bf16x8 bfrag;
                #pragma unroll
                for (int j = 0; j < 4; ++j) {
                    bfrag[j]     = (__bf16)(kfa[j] * kra[j]);
                    bfrag[4 + j] = (__bf16)(kfb[j] * krb[j]);
                }
                #pragma unroll
                for (int et = 0; et < 5; ++et)
                    acc[fa][et] = __builtin_amdgcn_mfma_f32_16x16x32_bf16(
                        bfrag, af[et], acc[fa][et], 0, 0, 0);
            }
        }
        // fragment-native coalesced write: elem ((wfa*5+et)*64+lane)*4+i
        // (e = 16et + (lane&15), f = 16wfa + 4(lane>>4) + i)
        __bf16* Gc = G + (size_t)(h * NCHUNK + c) * 20480;
        #pragma unroll
        for (int fa = 0; fa < 2; ++fa) {
            const int wfa = 2 * w + fa;
            #pragma unroll
            for (int et = 0; et < 5; ++et) {
                bf16x4 o;
                #pragma unroll
                for (int i = 0; i < 4; ++i) o[i] = (__bf16)acc[fa][et][i];
                *(bf16x4*)&Gc[((wfa * 5 + et) * 64 + lane) * 4] = o;
            }
        }
    }

    // ---- intra-chunk causal attention from LDS (Kl + Vt2 read-time permute) ----
    float qsel[8];
    #pragma unroll
    for (int j = 0; j < 8; ++j) qsel[j] = (g & 1) ? qr[8 + j] : qr[j];
    bf16x8 qfrag = {};
    if (g < 2) {
        #pragma unroll
        for (int j = 0; j < 8; ++j) qfrag[j] = (__bf16)qsel[j];
    }

    f32x4 oacc[4] = {};
    float zin = 0.f;
    const int qG = qb + r;
    const int smax = w >> 1;    // include 32-key subtiles sidx <= smax
    #pragma unroll
    for (int tl = 0; tl < 2; ++tl) {
        #pragma unroll
        for (int ks = 0; ks < 2; ++ks) {
            const int sidx = 2 * tl + ks;
            if (sidx <= smax) {
                const bool diag = (sidx == smax);
                bf16x8 kf[2];
                #pragma unroll
                for (int uk = 0; uk < 2; ++uk) {
                    bf16x8 f = {};
                    if (g < 2) {
                        const int key = 64 * tl + 32 * ks + 16 * uk + r;
                        f = *(const bf16x8*)(Kl + key * 32 + ((16 * g) ^ ((key & 1) << 4)));
                    }
                    kf[uk] = f;
                }
                const f32x4 zero4 = {};
                f32x4 s[2];
                #pragma unroll
                for (int uk = 0; uk < 2; ++uk)
                    s[uk] = __builtin_amdgcn_mfma_f32_16x16x32_bf16(kf[uk], qfrag, zero4, 0, 0, 0);

                bf16x8 pf;
                float zs = 0.f;
                const int k0g = k0 + 64 * tl + 32 * ks;
                #pragma unroll
                for (int uk = 0; uk < 2; ++uk) {
                    const int kGb = k0g + 16 * uk + 4 * g;
                    #pragma unroll
                    for (int i = 0; i < 4; ++i) {
                        const float sv = s[uk][i];
                        float p = ALPHA * sv * sv;
                        if (diag && (kGb + i > qG)) p = 0.f;
                        zs += p;
                        pf[4 * uk + i] = (__bf16)p;
                    }
                }
                zin += zs;
                #pragma unroll
                for (int dt = 0; dt < 4; ++dt) {
                    const int base = 128 * tl + 64 * ks + 8 * g;
                    u64x2 both;
                    both[0] = *(const u64*)(Vt2 + SW256(16 * dt + r, base));
                    both[1] = *(const u64*)(Vt2 + SW256(16 * dt + r, base + 32));
                    const bf16x8 vf = __builtin_bit_cast(bf16x8, both);
                    oacc[dt] = __builtin_amdgcn_mfma_f32_16x16x32_bf16(vf, pf, oacc[dt], 0, 0, 0);
                }
            }
        }
    }

    // ---- store fp32 intra-partial O and Z ----
    const int q = qb + r;
    #pragma unroll
    for (int dt = 0; dt < 4; ++dt)
        *(f32x4*)(Og + ((size_t)h * SEQN + q) * DVAL + 16 * dt + 4 * g) = oacc[dt];
    zin += __shfl_xor(zin, 16); zin += __shfl_xor(zin, 32);
    if (lane < 16) {
        float* zp = Og + (size_t)NHEAD * SEQN * DVAL + (size_t)h * SEQN + qb;
        zp[r] = zin;
    }

    // ---- last block of this head: scan G -> Hb (LDS-image order) ----
    __threadfence();                 // release: this block's G visible device-wide
    __syncthreads();
    if (tid == 0)
        isLast = (atomicAdd(&cnt[h], 1u) == (unsigned)(NCHUNK - 1));
    __syncthreads();
    if (isLast) {
        __threadfence();             // acquire: all head-h G writes visible
        const __bf16* Gh = G + (size_t)h * NCHUNK * 20480;
        unsigned char* Hh = (unsigned char*)(Hb + (size_t)h * NCHUNK * 20480);
        #pragma unroll
        for (int k2 = 0; k2 < 10; ++k2) {
            const int u = tid + 512 * k2;           // 4-elem unit, 0..5119
            const int lu = u & 63;
            const int ftet = u >> 6;                // wfa*5+et
            const int wfa = ftet / 5;
            const int et = ftet - 5 * wfa;
            const int e = 16 * et + (lu & 15);
            const int f = 16 * wfa + 4 * (lu >> 4);
            const int img = SW512(e, 2 * f);        // 8B-aligned image offset
            f32x4 acc = {};
            #pragma unroll
            for (int cc = 0; cc < NCHUNK; ++cc) {
                bf16x4 o;
                #pragma unroll
                for (int j = 0; j < 4; ++j) o[j] = (__bf16)acc[j];
                *(u64*)(Hh + (size_t)cc * 40960 + img) = __builtin_bit_cast(u64, o);
                const bf16x4 v = *(const bf16x4*)&Gh[(size_t)cc * 20480 + 4 * u];
                #pragma unroll
                for (int j = 0; j < 4; ++j) acc[j] += bf2f(v[j]);
            }
        }
    }
}

// ---------------- Phase 3s: streaming stage + state apply (O/Z RMW) ----------------
// grid 512 = (h = bid&7, c, qh), 256 thr (4 waves; wave w: queries qh*64+16w..+15).
__global__ __launch_bounds__(256, 2)
void p3s_apply(const float* __restrict__ Qg, const __bf16* __restrict__ Hb,
               float* __restrict__ Og)
{
    __shared__ __align__(128) unsigned char Hlds[80 * 512];   // LDS image (40KB)
    const int tid = threadIdx.x;
    const int lane = tid & 63;
    const int r = lane & 15, g = lane >> 4;
    const int w = tid >> 6;          // wave 0..3
    const int bid = blockIdx.x;
    const int h = bid & 7;
    const int x = bid >> 3;          // 0..63
    const int c = x >> 1;            // 0..31
    const int qh = x & 1;
    if (c == 0) return;              // partial is already final (uniform exit)
    const int qb = c * CHUNK + qh * 64 + 16 * w;
    const int q = qb + r;

    // ---- prefetch Q row + fp32 partials (in flight during stage) ----
    float qr[16];
    {
        const float* qp = Qg + ((size_t)h * SEQN + q) * DKEY;
        #pragma unroll
        for (int m = 0; m < 4; ++m) {
            const f32x4 v = *(const f32x4*)(qp + 4 * m);
            qr[4 * m + 0] = v[0]; qr[4 * m + 1] = v[1];
            qr[4 * m + 2] = v[2]; qr[4 * m + 3] = v[3];
        }
    }
    f32x4 oprev[4];
    #pragma unroll
    for (int dt = 0; dt < 4; ++dt)
        oprev[dt] = *(const f32x4*)(Og + ((size_t)h * SEQN + q) * DVAL + 16 * dt + 4 * g);
    float* zp = Og + (size_t)NHEAD * SEQN * DVAL + (size_t)h * SEQN + qb;
    const float zprev = zp[r];

    // ---- pure streaming copy: Hb image -> LDS (no decode) ----
    {
        const unsigned char* src = (const unsigned char*)(Hb + (size_t)(h * NCHUNK + c) * 20480);
        #pragma unroll
        for (int k2 = 0; k2 < 10; ++k2) {
            const int off = 16 * (tid + 256 * k2);
            *(u64x2*)(Hlds + off) = *(const u64x2*)(src + off);
        }
    }
    __syncthreads();

    // ---- state apply: O_state = Psi(q) x H_{<c} ----
    float qsel[8];
    #pragma unroll
    for (int j = 0; j < 8; ++j) qsel[j] = (g & 1) ? qr[8 + j] : qr[j];
    f32x4 oacc[4] = {};
    f32x4 zacc4 = {};
    #pragma unroll
    for (int ks = 0; ks < 8; ++ks) {
        const int t0 = 32 * ks + 8 * g;
        bf16x8 af[4];
        #pragma unroll
        for (int dt = 0; dt < 4; ++dt)
            af[dt] = *(const bf16x8*)(Hlds + SW512(16 * dt + r, t0 * 2));
        const bf16x8 afz = *(const bf16x8*)(Hlds + SW512(64 + r, t0 * 2));
        const float qi = ALPHA * ((g & 2) ? qr[2 * ks + 1] : qr[2 * ks]);
        bf16x8 pf;
        #pragma unroll
        for (int j = 0; j < 8; ++j) pf[j] = (__bf16)(qi * qsel[j]);
        #pragma unroll
        for (int dt = 0; dt < 4; ++dt)
            oacc[dt] = __builtin_amdgcn_mfma_f32_16x16x32_bf16(af[dt], pf, oacc[dt], 0, 0, 0);
        zacc4 = __builtin_amdgcn_mfma_f32_16x16x32_bf16(afz, pf, zacc4, 0, 0, 0);
    }

    // ---- final stores: O = intra partial + state ----
    #pragma unroll
    for (int dt = 0; dt < 4; ++dt) {
        f32x4 o = oprev[dt];
        #pragma unroll
        for (int i = 0; i < 4; ++i) o[i] += oacc[dt][i];
        *(f32x4*)(Og + ((size_t)h * SEQN + q) * DVAL + 16 * dt + 4 * g) = o;
    }
    if (lane < 16)   // g==0 lanes: zacc4[0] holds the e=64 (ones) row for query r
        zp[r] = zprev + zacc4[0];
}

// ---------------- Fallback (monolithic) if workspace too small ----------------
__global__ __launch_bounds__(128, 2)
void taylor_mono(const float* __restrict__ Qg, const float* __restrict__ Kg,
                 const float* __restrict__ Vg, float* __restrict__ Og)
{
    __shared__ __align__(16) __bf16 Kl[64 * 32];
    __shared__ __align__(16) __bf16 Vt[64 * 72];
    typedef __bf16 bf16x2 __attribute__((ext_vector_type(2)));
    const int tid = threadIdx.x;
    const int wv = tid >> 6;
    const int lane = tid & 63;
    const int r = lane & 15, g = lane >> 4;
    const int bid = blockIdx.x;
    const int h = bid & 7;
    const int tt = bid >> 3;
    const int qt = (tt & 1) ? (tt >> 1) : (63 - (tt >> 1));
    const int qb = qt * 64 + wv * 32;
    const float* __restrict__ Qh = Qg + (size_t)h * SEQN * DKEY;
    const float* __restrict__ Kh = Kg + (size_t)h * SEQN * DKEY;
    const float* __restrict__ Vh = Vg + (size_t)h * SEQN * DVAL;
    for (int row = tid; row < 64; row += 128) {
        bf16x8 z = {};
        *(bf16x8*)&Kl[row * 32 + 16] = z;
        *(bf16x8*)&Kl[row * 32 + 24] = z;
    }
    bf16x8 qfrag[2];
    #pragma unroll
    for (int uq = 0; uq < 2; ++uq) {
        bf16x8 f = {};
        if (g < 2) {
            const float* qp = Qh + (size_t)(qb + 16 * uq + r) * DKEY + 8 * g;
            const f32x4 a = *(const f32x4*)qp;
            const f32x4 b = *(const f32x4*)(qp + 4);
            #pragma unroll
            for (int j = 0; j < 4; ++j) { f[j] = (__bf16)a[j]; f[4 + j] = (__bf16)b[j]; }
        }
        qfrag[uq] = f;
    }
    f32x4 oacc[2][4] = {};
    float zacc0 = 0.f, zacc1 = 0.f;
    const int nkt = qt + 1;
    for (int kt = 0; kt < nkt; ++kt) {
        const int k0 = kt * 64;
        {
            const int key = tid >> 1, half = tid & 1;
            const float* kp = Kh + (size_t)(k0 + key) * DKEY + 8 * half;
            const f32x4 a = *(const f32x4*)kp;
            const f32x4 b = *(const f32x4*)(kp + 4);
            bf16x8 kb;
            #pragma unroll
            for (int j = 0; j < 4; ++j) { kb[j] = (__bf16)a[j]; kb[4 + j] = (__bf16)b[j]; }
            *(bf16x8*)&Kl[key * 32 + 8 * half] = kb;
        }
        {
            const int d = tid & 63;
            const int kp2 = (tid >> 6) * 2;
            #pragma unroll
            for (int i = 0; i < 16; ++i) {
                const int kk = i * 4 + kp2;
                const float a0 = Vh[(size_t)(k0 + kk) * DVAL + d];
                const float a1 = Vh[(size_t)(k0 + kk + 1) * DVAL + d];
                const int w32 = kk & 31;
                const int col = (kk & 32) + ((w32 >> 2) & 3) * 8 + ((w32 >> 4) << 2) + (kk & 3);
                bf16x2 p; p[0] = (__bf16)a0; p[1] = (__bf16)a1;
                *(bf16x2*)&Vt[d * 72 + col] = p;
            }
        }
        __syncthreads();
        const bool diag = (kt + 1 == nkt);
        #pragma unroll
        for (int ks = 0; ks < 2; ++ks) {
            if (k0 + 32 * ks < qb + 32) {
                bf16x8 vfrag[4];
                #pragma unroll
                for (int dt = 0; dt < 4; ++dt)
                    vfrag[dt] = *(const bf16x8*)&Vt[(16 * dt + r) * 72 + 32 * ks + 8 * g];
                bf16x8 kfr[2];
                #pragma unroll
                for (int uk = 0; uk < 2; ++uk)
                    kfr[uk] = *(const bf16x8*)&Kl[(32 * ks + 16 * uk + r) * 32 + 8 * g];
                const f32x4 zero4 = {};
                f32x4 s[2][2];
                #pragma unroll
                for (int uq = 0; uq < 2; ++uq)
                    #pragma unroll
                    for (int uk = 0; uk < 2; ++uk)
                        s[uq][uk] = __builtin_amdgcn_mfma_f32_16x16x32_bf16(
                            kfr[uk], qfrag[uq], zero4, 0, 0, 0);
                #pragma unroll
                for (int uq = 0; uq < 2; ++uq) {
                    bf16x8 pf;
                    float zs = 0.f;
                    #pragma unroll
                    for (int uk = 0; uk < 2; ++uk) {
                        const int kGb = k0 + 32 * ks + 16 * uk + 4 * g;
                        const int qG = qb + 16 * uq + r;
                        #pragma unroll
                        for (int i = 0; i < 4; ++i) {
                            const float sv = s[uq][uk][i];
                            float p = 0.03125f * sv * sv;
                            if (diag && (kGb + i > qG)) p = 0.f;
                            zs += p;
                            pf[4 * uk + i] = (__bf16)p;
                        }
                    }
                    if (uq == 0) zacc0 += zs; else zacc1 += zs;
                    #pragma unroll
                    for (int dt = 0; dt < 4; ++dt)
                        oacc[uq][dt] = __builtin_amdgcn_mfma_f32_16x16x32_bf16(
                            vfrag[dt], pf, oacc[uq][dt], 0, 0, 0);
                }
            }
        }
        __syncthreads();
    }
    #pragma unroll
    for (int uq = 0; uq < 2; ++uq) {
        const int q = qb + 16 * uq + r;
        #pragma unroll
        for (int dt = 0; dt < 4; ++dt) {
            float* op = Og + ((size_t)h * SEQN + q) * DVAL + 16 * dt + 4 * g;
            *(f32x4*)op = oacc[uq][dt];
        }
    }
    zacc0 += __shfl_xor(zacc0, 16); zacc0 += __shfl_xor(zacc0, 32);
    zacc1 += __shfl_xor(zacc1, 16); zacc1 += __shfl_xor(zacc1, 32);
    if (lane < 16) {
        float* zp = Og + (size_t)NHEAD * SEQN * DVAL + (size_t)h * SEQN + qb;
        zp[r] = zacc0;
        zp[16 + r] = zacc1;
    }
}

extern "C" void kernel_launch(void* const* d_in, const int* in_sizes, int n_in,
                              void* d_out, int out_size, void* d_ws, size_t ws_size,
                              hipStream_t stream) {
    const float* Q = (const float*)d_in[0];
    const float* K = (const float*)d_in[1];
    const float* V = (const float*)d_in[2];
    float* O = (float*)d_out;

    const size_t G_OFF   = 0;                      // 8*32*20480 bf16 = 10,485,760 B
    const size_t HB_OFF  = 10485760;               // LDS-image Hb, same size
    const size_t CNT_OFF = 20971520;               // 8 x u32 (+pad)
    const size_t NEED    = 20971584;

    if (ws_size >= NEED) {
        char* ws = (char*)d_ws;
        __bf16* G  = (__bf16*)(ws + G_OFF);
        __bf16* Hb = (__bf16*)(ws + HB_OFF);
        unsigned* cnt = (unsigned*)(ws + CNT_OFF);
        hipMemsetAsync((void*)cnt, 0, 64, stream);
        p01_fused<<<dim3(256), dim3(512), 0, stream>>>(K, V, Q, G, Hb, cnt, O);
        p3s_apply<<<dim3(512), dim3(256), 0, stream>>>(Q, Hb, O);
    } else {
        taylor_mono<<<dim3(512), dim3(128), 0, stream>>>(Q, K, V, O);
    }
}

// Round 14
// 28.246 us; speedup vs baseline: 5.0151x; 5.0151x over previous
//
#include <hip/hip_runtime.h>

// Causal quadratic linear attention, chunked-scan formulation.
//   (q.k)^2 = sum_{i,j} q_i q_j k_i k_j   (256 ordered-pair features, f = 16i+j)
// CHUNK=128, NCHUNK=32. THREE launches:
// p01   : stage K/V in LDS; chunk state G via operand-swapped MFMA, written
//         in FRAGMENT-NATIVE linear order (coalesced); intra-chunk causal
//         part from the staged LDS tiles -> fp32 O/Z partials in Og.
// p2scan: exclusive prefix over chunks, serial O(NCHUNK) scan; linear
//         coalesced reads AND writes (elementwise on fragment-native order).
// p3s   : per (h,c,qh) block (512 x 256 thr, 2/CU): tid-linear streaming
//         40KB Hb->LDS copy (zero decode), MFMA fragments read as 2x b64
//         at computed fragment-native unit offsets (conflict-free),
//         O += state RMW of p01's partials.

#define SEQN 4096
#define NHEAD 8
#define DKEY 16
#define DVAL 64
#define CHUNK 128
#define NCHUNK 32
#define ALPHA 0.03125f

typedef float f32x4 __attribute__((ext_vector_type(4)));
typedef __bf16 bf16x4 __attribute__((ext_vector_type(4)));
typedef __bf16 bf16x8 __attribute__((ext_vector_type(8)));
typedef unsigned long long u64;
typedef u64 u64x2 __attribute__((ext_vector_type(2)));

#define SW512(row, colb) (((row) << 9) + ((colb) ^ (((row) & 7) << 4)))
#define SW256(row, colb) (((row) << 8) + ((colb) ^ (((row) & 7) << 4)))

__device__ inline float bf2f(__bf16 x) {
    unsigned short u = __builtin_bit_cast(unsigned short, x);
    unsigned int v = ((unsigned int)u) << 16;
    return __builtin_bit_cast(float, v);
}

// ---------------- Phase 01: stage + chunk state + intra attention ----------------
// grid 256 = (h = bid&7, c = bid>>3), 512 thr (8 waves; wave w: queries 16w..+15).
__global__ __launch_bounds__(512, 1)
void p01_state(const float* __restrict__ Kg, const float* __restrict__ Vg,
               const float* __restrict__ Qg, __bf16* __restrict__ G,
               float* __restrict__ Og)
{
    __shared__ __align__(128) unsigned char Vt2[80 * 256];   // bf16 [80][128], swz (20KB)
    __shared__ __align__(128) unsigned char Ktf[16 * 512];   // f32  [16][128], swz (8KB)
    __shared__ __align__(128) unsigned char Kl[128 * 32];    // bf16 [128][16], swz (4KB)
    const int tid = threadIdx.x;
    const int w = tid >> 6;          // wave 0..7
    const int lane = tid & 63;
    const int r = lane & 15, g = lane >> 4;
    const int bid = blockIdx.x;
    const int h = bid & 7, c = bid >> 3;              // c: 0..31
    const int k0 = c * CHUNK;
    const int qb = k0 + 16 * w;

    // ---- Q row load (issued early, in flight during staging) ----
    float qr[16];
    {
        const float* qp = Qg + ((size_t)h * SEQN + qb + r) * DKEY;
        #pragma unroll
        for (int m = 0; m < 4; ++m) {
            const f32x4 v = *(const f32x4*)(qp + 4 * m);
            qr[4 * m + 0] = v[0]; qr[4 * m + 1] = v[1];
            qr[4 * m + 2] = v[2]; qr[4 * m + 3] = v[3];
        }
    }

    // ---- stage K: Ktf (f32 transposed, swz) + Kl (bf16 row-major, swz) ----
    {
        const int key = tid >> 2, part = tid & 3;
        const float* kp = Kg + ((size_t)h * SEQN + k0 + key) * DKEY + 4 * part;
        const f32x4 a = *(const f32x4*)kp;
        #pragma unroll
        for (int j = 0; j < 4; ++j)
            *(float*)(Ktf + SW512(4 * part + j, key * 4)) = a[j];
        bf16x4 o;
        #pragma unroll
        for (int j = 0; j < 4; ++j) o[j] = (__bf16)a[j];
        *(bf16x4*)(Kl + key * 32 + ((8 * part) ^ ((key & 1) << 4))) = o;
    }
    // ---- stage V rows 0..63 (dim el, cols t, swz) ----
    {
        const int el = tid & 63;
        const int seg = tid >> 6;
        const float* __restrict__ Vh = Vg + (size_t)h * SEQN * DVAL;
        #pragma unroll
        for (int p = 0; p < 2; ++p) {
            const int tb = 8 * (seg + 8 * p);    // 0..120
            bf16x8 v;
            #pragma unroll
            for (int j = 0; j < 8; ++j)
                v[j] = (__bf16)Vh[(size_t)(k0 + tb + j) * DVAL + el];
            *(bf16x8*)(Vt2 + SW256(el, tb * 2)) = v;
        }
    }
    // ---- rows 64..79: ones (row 64) / zeros ----
    {
        const int row = 64 + (tid >> 5);
        const int i = tid & 31;
        const u64 val = (row == 64) ? 0x3F803F803F803F80ULL : 0ULL;
        *(u64*)(Vt2 + SW256(row, 8 * i)) = val;
    }
    __syncthreads();

    // ---- MFMA: G[e][f]; wave w owns f-tiles 2w, 2w+1 (operand-swapped) ----
    {
        f32x4 acc[2][5] = {};
        #pragma unroll
        for (int ks = 0; ks < 4; ++ks) {
            const int t0 = 32 * ks + 8 * g;
            bf16x8 af[5];
            #pragma unroll
            for (int et = 0; et < 5; ++et)
                af[et] = *(const bf16x8*)(Vt2 + SW256(16 * et + r, t0 * 2));
            const f32x4 kra = *(const f32x4*)(Ktf + SW512(r, t0 * 4));
            const f32x4 krb = *(const f32x4*)(Ktf + SW512(r, t0 * 4 + 16));
            #pragma unroll
            for (int fa = 0; fa < 2; ++fa) {
                const int ft = 2 * w + fa;
                const f32x4 kfa = *(const f32x4*)(Ktf + SW512(ft, t0 * 4));
                const f32x4 kfb = *(const f32x4*)(Ktf + SW512(ft, t0 * 4 + 16));
                bf16x8 bfrag;
                #pragma unroll
                for (int j = 0; j < 4; ++j) {
                    bfrag[j]     = (__bf16)(kfa[j] * kra[j]);
                    bfrag[4 + j] = (__bf16)(kfb[j] * krb[j]);
                }
                #pragma unroll
                for (int et = 0; et < 5; ++et)
                    acc[fa][et] = __builtin_amdgcn_mfma_f32_16x16x32_bf16(
                        bfrag, af[et], acc[fa][et], 0, 0, 0);
            }
        }
        // fragment-native coalesced write: elem ((wfa*5+et)*64+lane)*4+i
        // (e = 16et + (lane&15), f = 16wfa + 4(lane>>4) + i)
        __bf16* Gc = G + (size_t)(h * NCHUNK + c) * 20480;
        #pragma unroll
        for (int fa = 0; fa < 2; ++fa) {
            const int wfa = 2 * w + fa;
            #pragma unroll
            for (int et = 0; et < 5; ++et) {
                bf16x4 o;
                #pragma unroll
                for (int i = 0; i < 4; ++i) o[i] = (__bf16)acc[fa][et][i];
                *(bf16x4*)&Gc[((wfa * 5 + et) * 64 + lane) * 4] = o;
            }
        }
    }

    // ---- intra-chunk causal attention from LDS (Kl + Vt2 read-time permute) ----
    float qsel[8];
    #pragma unroll
    for (int j = 0; j < 8; ++j) qsel[j] = (g & 1) ? qr[8 + j] : qr[j];
    bf16x8 qfrag = {};
    if (g < 2) {
        #pragma unroll
        for (int j = 0; j < 8; ++j) qfrag[j] = (__bf16)qsel[j];
    }

    f32x4 oacc[4] = {};
    float zin = 0.f;
    const int qG = qb + r;
    const int smax = w >> 1;    // include 32-key subtiles sidx <= smax
    #pragma unroll
    for (int tl = 0; tl < 2; ++tl) {
        #pragma unroll
        for (int ks = 0; ks < 2; ++ks) {
            const int sidx = 2 * tl + ks;
            if (sidx <= smax) {
                const bool diag = (sidx == smax);
                bf16x8 kf[2];
                #pragma unroll
                for (int uk = 0; uk < 2; ++uk) {
                    bf16x8 f = {};
                    if (g < 2) {
                        const int key = 64 * tl + 32 * ks + 16 * uk + r;
                        f = *(const bf16x8*)(Kl + key * 32 + ((16 * g) ^ ((key & 1) << 4)));
                    }
                    kf[uk] = f;
                }
                const f32x4 zero4 = {};
                f32x4 s[2];
                #pragma unroll
                for (int uk = 0; uk < 2; ++uk)
                    s[uk] = __builtin_amdgcn_mfma_f32_16x16x32_bf16(kf[uk], qfrag, zero4, 0, 0, 0);

                bf16x8 pf;
                float zs = 0.f;
                const int k0g = k0 + 64 * tl + 32 * ks;
                #pragma unroll
                for (int uk = 0; uk < 2; ++uk) {
                    const int kGb = k0g + 16 * uk + 4 * g;
                    #pragma unroll
                    for (int i = 0; i < 4; ++i) {
                        const float sv = s[uk][i];
                        float p = ALPHA * sv * sv;
                        if (diag && (kGb + i > qG)) p = 0.f;
                        zs += p;
                        pf[4 * uk + i] = (__bf16)p;
                    }
                }
                zin += zs;
                #pragma unroll
                for (int dt = 0; dt < 4; ++dt) {
                    const int base = 128 * tl + 64 * ks + 8 * g;
                    u64x2 both;
                    both[0] = *(const u64*)(Vt2 + SW256(16 * dt + r, base));
                    both[1] = *(const u64*)(Vt2 + SW256(16 * dt + r, base + 32));
                    const bf16x8 vf = __builtin_bit_cast(bf16x8, both);
                    oacc[dt] = __builtin_amdgcn_mfma_f32_16x16x32_bf16(vf, pf, oacc[dt], 0, 0, 0);
                }
            }
        }
    }

    // ---- store fp32 intra-partial O and Z ----
    const int q = qb + r;
    #pragma unroll
    for (int dt = 0; dt < 4; ++dt)
        *(f32x4*)(Og + ((size_t)h * SEQN + q) * DVAL + 16 * dt + 4 * g) = oacc[dt];
    zin += __shfl_xor(zin, 16); zin += __shfl_xor(zin, 32);
    if (lane < 16) {
        float* zp = Og + (size_t)NHEAD * SEQN * DVAL + (size_t)h * SEQN + qb;
        zp[r] = zin;
    }
}

// ---------------- Phase 2: exclusive prefix, serial O(NCHUNK) scan ----------------
// grid 160 = (h = bid&7, fb = bid>>3 in 0..19), 256 thr, 4 elems/thread.
// Elementwise, fully linear/coalesced on the fragment-native layout.
__global__ __launch_bounds__(256)
void p2_scan(const __bf16* __restrict__ G, __bf16* __restrict__ Hb)
{
    const int h = blockIdx.x & 7;
    const int fb = blockIdx.x >> 3;                 // 0..19
    const int fid = fb * 1024 + 4 * threadIdx.x;    // 0..20476
    const __bf16* Gh = G + (size_t)h * NCHUNK * 20480 + fid;
    __bf16* Hh = Hb + (size_t)h * NCHUNK * 20480 + fid;
    f32x4 acc = {};
    #pragma unroll
    for (int cc = 0; cc < NCHUNK; ++cc) {
        bf16x4 o;
        #pragma unroll
        for (int j = 0; j < 4; ++j) o[j] = (__bf16)acc[j];
        *(u64*)&Hh[(size_t)cc * 20480] = __builtin_bit_cast(u64, o);
        const bf16x4 v = *(const bf16x4*)&Gh[(size_t)cc * 20480];
        #pragma unroll
        for (int j = 0; j < 4; ++j) acc[j] += bf2f(v[j]);
    }
}

// ---------------- Phase 3s: linear stage + frag-native state apply (O/Z RMW) ----------------
// grid 512 = (h = bid&7, c, qh), 256 thr (4 waves; wave w: queries qh*64+16w..+15).
// Hlds holds the chunk's Hb verbatim (fragment-native). Element (e,f) lives at
// byte 8*[(wfa*5+et)*64 + lsel*16 + (e&15)], wfa=f>>4, et=e>>4, lsel=(f&15)>>2.
// MFMA A-frag for lane (r,g), dt, ks: two b64 at (wfa*5+dt)*512 + (g&1)*256 + 8r, +128.
__global__ __launch_bounds__(256, 2)
void p3s_apply(const float* __restrict__ Qg, const __bf16* __restrict__ Hb,
               float* __restrict__ Og)
{
    __shared__ __align__(128) unsigned char Hlds[40960];   // fragment-native (40KB)
    const int tid = threadIdx.x;
    const int lane = tid & 63;
    const int r = lane & 15, g = lane >> 4;
    const int w = tid >> 6;          // wave 0..3
    const int bid = blockIdx.x;
    const int h = bid & 7;
    const int x = bid >> 3;          // 0..63
    const int c = x >> 1;            // 0..31
    const int qh = x & 1;
    if (c == 0) return;              // partial is already final (uniform exit)
    const int qb = c * CHUNK + qh * 64 + 16 * w;
    const int q = qb + r;

    // ---- prefetch Q row + fp32 partials (in flight during stage) ----
    float qr[16];
    {
        const float* qp = Qg + ((size_t)h * SEQN + q) * DKEY;
        #pragma unroll
        for (int m = 0; m < 4; ++m) {
            const f32x4 v = *(const f32x4*)(qp + 4 * m);
            qr[4 * m + 0] = v[0]; qr[4 * m + 1] = v[1];
            qr[4 * m + 2] = v[2]; qr[4 * m + 3] = v[3];
        }
    }
    f32x4 oprev[4];
    #pragma unroll
    for (int dt = 0; dt < 4; ++dt)
        oprev[dt] = *(const f32x4*)(Og + ((size_t)h * SEQN + q) * DVAL + 16 * dt + 4 * g);
    float* zp = Og + (size_t)NHEAD * SEQN * DVAL + (size_t)h * SEQN + qb;
    const float zprev = zp[r];

    // ---- pure tid-linear streaming copy: Hb chunk -> LDS (no decode) ----
    {
        const unsigned char* src = (const unsigned char*)(Hb + (size_t)(h * NCHUNK + c) * 20480);
        #pragma unroll
        for (int k2 = 0; k2 < 10; ++k2) {
            const int off = 16 * (tid + 256 * k2);
            *(u64x2*)(Hlds + off) = *(const u64x2*)(src + off);
        }
    }
    __syncthreads();

    // ---- state apply: O_state = Psi(q) x H_{<c} ----
    float qsel[8];
    #pragma unroll
    for (int j = 0; j < 8; ++j) qsel[j] = (g & 1) ? qr[8 + j] : qr[j];
    f32x4 oacc[4] = {};
    f32x4 zacc4 = {};
    const int gsel = (g & 1) * 256 + 8 * r;   // lane's byte offset within a (wfa,et) panel
    #pragma unroll
    for (int ks = 0; ks < 8; ++ks) {
        const int wfa = 2 * ks + (g >> 1);
        const int pbase = wfa * 2560 + gsel;  // (wfa*5+0)*512 + gsel
        bf16x8 af[4];
        #pragma unroll
        for (int dt = 0; dt < 4; ++dt) {
            u64x2 both;
            both[0] = *(const u64*)(Hlds + pbase + dt * 512);
            both[1] = *(const u64*)(Hlds + pbase + dt * 512 + 128);
            af[dt] = __builtin_bit_cast(bf16x8, both);
        }
        u64x2 bz;
        bz[0] = *(const u64*)(Hlds + pbase + 4 * 512);
        bz[1] = *(const u64*)(Hlds + pbase + 4 * 512 + 128);
        const bf16x8 afz = __builtin_bit_cast(bf16x8, bz);

        const float qi = ALPHA * ((g & 2) ? qr[2 * ks + 1] : qr[2 * ks]);
        bf16x8 pf;
        #pragma unroll
        for (int j = 0; j < 8; ++j) pf[j] = (__bf16)(qi * qsel[j]);
        #pragma unroll
        for (int dt = 0; dt < 4; ++dt)
            oacc[dt] = __builtin_amdgcn_mfma_f32_16x16x32_bf16(af[dt], pf, oacc[dt], 0, 0, 0);
        zacc4 = __builtin_amdgcn_mfma_f32_16x16x32_bf16(afz, pf, zacc4, 0, 0, 0);
    }

    // ---- final stores: O = intra partial + state ----
    #pragma unroll
    for (int dt = 0; dt < 4; ++dt) {
        f32x4 o = oprev[dt];
        #pragma unroll
        for (int i = 0; i < 4; ++i) o[i] += oacc[dt][i];
        *(f32x4*)(Og + ((size_t)h * SEQN + q) * DVAL + 16 * dt + 4 * g) = o;
    }
    if (lane < 16)   // g==0 lanes: zacc4[0] holds the e=64 (ones) row for query r
        zp[r] = zprev + zacc4[0];
}

// ---------------- Fallback (monolithic) if workspace too small ----------------
__global__ __launch_bounds__(128, 2)
void taylor_mono(const float* __restrict__ Qg, const float* __restrict__ Kg,
                 const float* __restrict__ Vg, float* __restrict__ Og)
{
    __shared__ __align__(16) __bf16 Kl[64 * 32];
    __shared__ __align__(16) __bf16 Vt[64 * 72];
    typedef __bf16 bf16x2 __attribute__((ext_vector_type(2)));
    const int tid = threadIdx.x;
    const int wv = tid >> 6;
    const int lane = tid & 63;
    const int r = lane & 15, g = lane >> 4;
    const int bid = blockIdx.x;
    const int h = bid & 7;
    const int tt = bid >> 3;
    const int qt = (tt & 1) ? (tt >> 1) : (63 - (tt >> 1));
    const int qb = qt * 64 + wv * 32;
    const float* __restrict__ Qh = Qg + (size_t)h * SEQN * DKEY;
    const float* __restrict__ Kh = Kg + (size_t)h * SEQN * DKEY;
    const float* __restrict__ Vh = Vg + (size_t)h * SEQN * DVAL;
    for (int row = tid; row < 64; row += 128) {
        bf16x8 z = {};
        *(bf16x8*)&Kl[row * 32 + 16] = z;
        *(bf16x8*)&Kl[row * 32 + 24] = z;
    }
    bf16x8 qfrag[2];
    #pragma unroll
    for (int uq = 0; uq < 2; ++uq) {
        bf16x8 f = {};
        if (g < 2) {
            const float* qp = Qh + (size_t)(qb + 16 * uq + r) * DKEY + 8 * g;
            const f32x4 a = *(const f32x4*)qp;
            const f32x4 b = *(const f32x4*)(qp + 4);
            #pragma unroll
            for (int j = 0; j < 4; ++j) { f[j] = (__bf16)a[j]; f[4 + j] = (__bf16)b[j]; }
        }
        qfrag[uq] = f;
    }
    f32x4 oacc[2][4] = {};
    float zacc0 = 0.f, zacc1 = 0.f;
    const int nkt = qt + 1;
    for (int kt = 0; kt < nkt; ++kt) {
        const int k0 = kt * 64;
        {
            const int key = tid >> 1, half = tid & 1;
            const float* kp = Kh + (size_t)(k0 + key) * DKEY + 8 * half;
            const f32x4 a = *(const f32x4*)kp;
            const f32x4 b = *(const f32x4*)(kp + 4);
            bf16x8 kb;
            #pragma unroll
            for (int j = 0; j < 4; ++j) { kb[j] = (__bf16)a[j]; kb[4 + j] = (__bf16)b[j]; }
            *(bf16x8*)&Kl[key * 32 + 8 * half] = kb;
        }
        {
            const int d = tid & 63;
            const int kp2 = (tid >> 6) * 2;
            #pragma unroll
            for (int i = 0; i < 16; ++i) {
                const int kk = i * 4 + kp2;
                const float a0 = Vh[(size_t)(k0 + kk) * DVAL + d];
                const float a1 = Vh[(size_t)(k0 + kk + 1) * DVAL + d];
                const int w32 = kk & 31;
                const int col = (kk & 32) + ((w32 >> 2) & 3) * 8 + ((w32 >> 4) << 2) + (kk & 3);
                bf16x2 p; p[0] = (__bf16)a0; p[1] = (__bf16)a1;
                *(bf16x2*)&Vt[d * 72 + col] = p;
            }
        }
        __syncthreads();
        const bool diag = (kt + 1 == nkt);
        #pragma unroll
        for (int ks = 0; ks < 2; ++ks) {
            if (k0 + 32 * ks < qb + 32) {
                bf16x8 vfrag[4];
                #pragma unroll
                for (int dt = 0; dt < 4; ++dt)
                    vfrag[dt] = *(const bf16x8*)&Vt[(16 * dt + r) * 72 + 32 * ks + 8 * g];
                bf16x8 kfr[2];
                #pragma unroll
                for (int uk = 0; uk < 2; ++uk)
                    kfr[uk] = *(const bf16x8*)&Kl[(32 * ks + 16 * uk + r) * 32 + 8 * g];
                const f32x4 zero4 = {};
                f32x4 s[2][2];
                #pragma unroll
                for (int uq = 0; uq < 2; ++uq)
                    #pragma unroll
                    for (int uk = 0; uk < 2; ++uk)
                        s[uq][uk] = __builtin_amdgcn_mfma_f32_16x16x32_bf16(
                            kfr[uk], qfrag[uq], zero4, 0, 0, 0);
                #pragma unroll
                for (int uq = 0; uq < 2; ++uq) {
                    bf16x8 pf;
                    float zs = 0.f;
                    #pragma unroll
                    for (int uk = 0; uk < 2; ++uk) {
                        const int kGb = k0 + 32 * ks + 16 * uk + 4 * g;
                        const int qG = qb + 16 * uq + r;
                        #pragma unroll
                        for (int i = 0; i < 4; ++i) {
                            const float sv = s[uq][uk][i];
                            float p = 0.03125f * sv * sv;
                            if (diag && (kGb + i > qG)) p = 0.f;
                            zs += p;
                            pf[4 * uk + i] = (__bf16)p;
                        }
                    }
                    if (uq == 0) zacc0 += zs; else zacc1 += zs;
                    #pragma unroll
                    for (int dt = 0; dt < 4; ++dt)
                        oacc[uq][dt] = __builtin_amdgcn_mfma_f32_16x16x32_bf16(
                            vfrag[dt], pf, oacc[uq][dt], 0, 0, 0);
                }
            }
        }
        __syncthreads();
    }
    #pragma unroll
    for (int uq = 0; uq < 2; ++uq) {
        const int q = qb + 16 * uq + r;
        #pragma unroll
        for (int dt = 0; dt < 4; ++dt) {
            float* op = Og + ((size_t)h * SEQN + q) * DVAL + 16 * dt + 4 * g;
            *(f32x4*)op = oacc[uq][dt];
        }
    }
    zacc0 += __shfl_xor(zacc0, 16); zacc0 += __shfl_xor(zacc0, 32);
    zacc1 += __shfl_xor(zacc1, 16); zacc1 += __shfl_xor(zacc1, 32);
    if (lane < 16) {
        float* zp = Og + (size_t)NHEAD * SEQN * DVAL + (size_t)h * SEQN + qb;
        zp[r] = zacc0;
        zp[16 + r] = zacc1;
    }
}

extern "C" void kernel_launch(void* const* d_in, const int* in_sizes, int n_in,
                              void* d_out, int out_size, void* d_ws, size_t ws_size,
                              hipStream_t stream) {
    const float* Q = (const float*)d_in[0];
    const float* K = (const float*)d_in[1];
    const float* V = (const float*)d_in[2];
    float* O = (float*)d_out;

    const size_t G_OFF  = 0;                       // 8*32*20480 bf16 = 10,485,760 B
    const size_t HB_OFF = 10485760;                // same size, fragment-native
    const size_t NEED   = 20971520;

    if (ws_size >= NEED) {
        char* ws = (char*)d_ws;
        __bf16* G  = (__bf16*)(ws + G_OFF);
        __bf16* Hb = (__bf16*)(ws + HB_OFF);
        p01_state<<<dim3(256), dim3(512), 0, stream>>>(K, V, Q, G, O);
        p2_scan  <<<dim3(160), dim3(256), 0, stream>>>(G, Hb);
        p3s_apply<<<dim3(512), dim3(256), 0, stream>>>(Q, Hb, O);
    } else {
        taylor_mono<<<dim3(512), dim3(128), 0, stream>>>(Q, K, V, O);
    }
}

// Round 15
// 27.674 us; speedup vs baseline: 5.1187x; 1.0207x over previous
//
#include <hip/hip_runtime.h>

// Causal quadratic linear attention, chunked-scan formulation.
//   (q.k)^2 = sum_{i,j} q_i q_j k_i k_j   (256 ordered-pair features, f = 16i+j)
// CHUNK=128, NCHUNK=32. THREE launches:
// p01   : stage K/V in LDS; chunk state G via operand-swapped MFMA, written
//         in FRAGMENT-NATIVE linear order (coalesced); intra-chunk causal
//         part from the staged LDS tiles -> bf16 O/Z PARTIALS in ws.
// p2scan: exclusive prefix over chunks, serial O(NCHUNK) scan; linear
//         coalesced reads AND writes (elementwise on fragment-native order);
//         writes zeros for c=0.
// p3s   : per (h,c,qh) block (512 x 256 thr, 2/CU): tid-linear streaming
//         40KB Hb->LDS copy (zero decode), MFMA fragments read as 2x b64
//         at computed fragment-native unit offsets (conflict-free),
//         final O = bf16 partial + state (Og write-once, never re-read).

#define SEQN 4096
#define NHEAD 8
#define DKEY 16
#define DVAL 64
#define CHUNK 128
#define NCHUNK 32
#define ALPHA 0.03125f

typedef float f32x4 __attribute__((ext_vector_type(4)));
typedef __bf16 bf16x4 __attribute__((ext_vector_type(4)));
typedef __bf16 bf16x8 __attribute__((ext_vector_type(8)));
typedef unsigned long long u64;
typedef u64 u64x2 __attribute__((ext_vector_type(2)));

#define SW512(row, colb) (((row) << 9) + ((colb) ^ (((row) & 7) << 4)))
#define SW256(row, colb) (((row) << 8) + ((colb) ^ (((row) & 7) << 4)))

__device__ inline float bf2f(__bf16 x) {
    unsigned short u = __builtin_bit_cast(unsigned short, x);
    unsigned int v = ((unsigned int)u) << 16;
    return __builtin_bit_cast(float, v);
}

// ---------------- Phase 01: stage + chunk state + intra attention ----------------
// grid 256 = (h = bid&7, c = bid>>3), 512 thr (8 waves; wave w: queries 16w..+15).
__global__ __launch_bounds__(512, 1)
void p01_state(const float* __restrict__ Kg, const float* __restrict__ Vg,
               const float* __restrict__ Qg, __bf16* __restrict__ G,
               __bf16* __restrict__ Op, __bf16* __restrict__ Zp)
{
    __shared__ __align__(128) unsigned char Vt2[80 * 256];   // bf16 [80][128], swz (20KB)
    __shared__ __align__(128) unsigned char Ktf[16 * 512];   // f32  [16][128], swz (8KB)
    __shared__ __align__(128) unsigned char Kl[128 * 32];    // bf16 [128][16], swz (4KB)
    const int tid = threadIdx.x;
    const int w = tid >> 6;          // wave 0..7
    const int lane = tid & 63;
    const int r = lane & 15, g = lane >> 4;
    const int bid = blockIdx.x;
    const int h = bid & 7, c = bid >> 3;              // c: 0..31
    const int k0 = c * CHUNK;
    const int qb = k0 + 16 * w;

    // ---- Q row load (issued early, in flight during staging) ----
    float qr[16];
    {
        const float* qp = Qg + ((size_t)h * SEQN + qb + r) * DKEY;
        #pragma unroll
        for (int m = 0; m < 4; ++m) {
            const f32x4 v = *(const f32x4*)(qp + 4 * m);
            qr[4 * m + 0] = v[0]; qr[4 * m + 1] = v[1];
            qr[4 * m + 2] = v[2]; qr[4 * m + 3] = v[3];
        }
    }

    // ---- stage K: Ktf (f32 transposed, swz) + Kl (bf16 row-major, swz) ----
    {
        const int key = tid >> 2, part = tid & 3;
        const float* kp = Kg + ((size_t)h * SEQN + k0 + key) * DKEY + 4 * part;
        const f32x4 a = *(const f32x4*)kp;
        #pragma unroll
        for (int j = 0; j < 4; ++j)
            *(float*)(Ktf + SW512(4 * part + j, key * 4)) = a[j];
        bf16x4 o;
        #pragma unroll
        for (int j = 0; j < 4; ++j) o[j] = (__bf16)a[j];
        *(bf16x4*)(Kl + key * 32 + ((8 * part) ^ ((key & 1) << 4))) = o;
    }
    // ---- stage V rows 0..63 (dim el, cols t, swz) ----
    {
        const int el = tid & 63;
        const int seg = tid >> 6;
        const float* __restrict__ Vh = Vg + (size_t)h * SEQN * DVAL;
        #pragma unroll
        for (int p = 0; p < 2; ++p) {
            const int tb = 8 * (seg + 8 * p);    // 0..120
            bf16x8 v;
            #pragma unroll
            for (int j = 0; j < 8; ++j)
                v[j] = (__bf16)Vh[(size_t)(k0 + tb + j) * DVAL + el];
            *(bf16x8*)(Vt2 + SW256(el, tb * 2)) = v;
        }
    }
    // ---- rows 64..79: ones (row 64) / zeros ----
    {
        const int row = 64 + (tid >> 5);
        const int i = tid & 31;
        const u64 val = (row == 64) ? 0x3F803F803F803F80ULL : 0ULL;
        *(u64*)(Vt2 + SW256(row, 8 * i)) = val;
    }
    __syncthreads();

    // ---- MFMA: G[e][f]; wave w owns f-tiles 2w, 2w+1 (operand-swapped) ----
    {
        f32x4 acc[2][5] = {};
        #pragma unroll
        for (int ks = 0; ks < 4; ++ks) {
            const int t0 = 32 * ks + 8 * g;
            bf16x8 af[5];
            #pragma unroll
            for (int et = 0; et < 5; ++et)
                af[et] = *(const bf16x8*)(Vt2 + SW256(16 * et + r, t0 * 2));
            const f32x4 kra = *(const f32x4*)(Ktf + SW512(r, t0 * 4));
            const f32x4 krb = *(const f32x4*)(Ktf + SW512(r, t0 * 4 + 16));
            #pragma unroll
            for (int fa = 0; fa < 2; ++fa) {
                const int ft = 2 * w + fa;
                const f32x4 kfa = *(const f32x4*)(Ktf + SW512(ft, t0 * 4));
                const f32x4 kfb = *(const f32x4*)(Ktf + SW512(ft, t0 * 4 + 16));
                bf16x8 bfrag;
                #pragma unroll
                for (int j = 0; j < 4; ++j) {
                    bfrag[j]     = (__bf16)(kfa[j] * kra[j]);
                    bfrag[4 + j] = (__bf16)(kfb[j] * krb[j]);
                }
                #pragma unroll
                for (int et = 0; et < 5; ++et)
                    acc[fa][et] = __builtin_amdgcn_mfma_f32_16x16x32_bf16(
                        bfrag, af[et], acc[fa][et], 0, 0, 0);
            }
        }
        // fragment-native coalesced write: elem ((wfa*5+et)*64+lane)*4+i
        // (e = 16et + (lane&15), f = 16wfa + 4(lane>>4) + i)
        __bf16* Gc = G + (size_t)(h * NCHUNK + c) * 20480;
        #pragma unroll
        for (int fa = 0; fa < 2; ++fa) {
            const int wfa = 2 * w + fa;
            #pragma unroll
            for (int et = 0; et < 5; ++et) {
                bf16x4 o;
                #pragma unroll
                for (int i = 0; i < 4; ++i) o[i] = (__bf16)acc[fa][et][i];
                *(bf16x4*)&Gc[((wfa * 5 + et) * 64 + lane) * 4] = o;
            }
        }
    }

    // ---- intra-chunk causal attention from LDS (Kl + Vt2 read-time permute) ----
    float qsel[8];
    #pragma unroll
    for (int j = 0; j < 8; ++j) qsel[j] = (g & 1) ? qr[8 + j] : qr[j];
    bf16x8 qfrag = {};
    if (g < 2) {
        #pragma unroll
        for (int j = 0; j < 8; ++j) qfrag[j] = (__bf16)qsel[j];
    }

    f32x4 oacc[4] = {};
    float zin = 0.f;
    const int qG = qb + r;
    const int smax = w >> 1;    // include 32-key subtiles sidx <= smax
    #pragma unroll
    for (int tl = 0; tl < 2; ++tl) {
        #pragma unroll
        for (int ks = 0; ks < 2; ++ks) {
            const int sidx = 2 * tl + ks;
            if (sidx <= smax) {
                const bool diag = (sidx == smax);
                bf16x8 kf[2];
                #pragma unroll
                for (int uk = 0; uk < 2; ++uk) {
                    bf16x8 f = {};
                    if (g < 2) {
                        const int key = 64 * tl + 32 * ks + 16 * uk + r;
                        f = *(const bf16x8*)(Kl + key * 32 + ((16 * g) ^ ((key & 1) << 4)));
                    }
                    kf[uk] = f;
                }
                const f32x4 zero4 = {};
                f32x4 s[2];
                #pragma unroll
                for (int uk = 0; uk < 2; ++uk)
                    s[uk] = __builtin_amdgcn_mfma_f32_16x16x32_bf16(kf[uk], qfrag, zero4, 0, 0, 0);

                bf16x8 pf;
                float zs = 0.f;
                const int k0g = k0 + 64 * tl + 32 * ks;
                #pragma unroll
                for (int uk = 0; uk < 2; ++uk) {
                    const int kGb = k0g + 16 * uk + 4 * g;
                    #pragma unroll
                    for (int i = 0; i < 4; ++i) {
                        const float sv = s[uk][i];
                        float p = ALPHA * sv * sv;
                        if (diag && (kGb + i > qG)) p = 0.f;
                        zs += p;
                        pf[4 * uk + i] = (__bf16)p;
                    }
                }
                zin += zs;
                #pragma unroll
                for (int dt = 0; dt < 4; ++dt) {
                    const int base = 128 * tl + 64 * ks + 8 * g;
                    u64x2 both;
                    both[0] = *(const u64*)(Vt2 + SW256(16 * dt + r, base));
                    both[1] = *(const u64*)(Vt2 + SW256(16 * dt + r, base + 32));
                    const bf16x8 vf = __builtin_bit_cast(bf16x8, both);
                    oacc[dt] = __builtin_amdgcn_mfma_f32_16x16x32_bf16(vf, pf, oacc[dt], 0, 0, 0);
                }
            }
        }
    }

    // ---- store bf16 intra-partial O and Z to ws (coalesced 8B/lane) ----
    const int q = qb + r;
    #pragma unroll
    for (int dt = 0; dt < 4; ++dt) {
        bf16x4 o;
        #pragma unroll
        for (int i = 0; i < 4; ++i) o[i] = (__bf16)oacc[dt][i];
        *(bf16x4*)&Op[((size_t)h * SEQN + q) * DVAL + 16 * dt + 4 * g] = o;
    }
    zin += __shfl_xor(zin, 16); zin += __shfl_xor(zin, 32);
    if (lane < 16)
        Zp[(size_t)h * SEQN + qb + r] = (__bf16)zin;
}

// ---------------- Phase 2: exclusive prefix, serial O(NCHUNK) scan ----------------
// grid 160 = (h = bid&7, fb = bid>>3 in 0..19), 256 thr, 4 elems/thread.
// Elementwise, fully linear/coalesced on the fragment-native layout.
// Writes zeros for c=0 (so p3s needs no branch).
__global__ __launch_bounds__(256)
void p2_scan(const __bf16* __restrict__ G, __bf16* __restrict__ Hb)
{
    const int h = blockIdx.x & 7;
    const int fb = blockIdx.x >> 3;                 // 0..19
    const int fid = fb * 1024 + 4 * threadIdx.x;    // 0..20476
    const __bf16* Gh = G + (size_t)h * NCHUNK * 20480 + fid;
    __bf16* Hh = Hb + (size_t)h * NCHUNK * 20480 + fid;
    f32x4 acc = {};
    #pragma unroll
    for (int cc = 0; cc < NCHUNK; ++cc) {
        bf16x4 o;
        #pragma unroll
        for (int j = 0; j < 4; ++j) o[j] = (__bf16)acc[j];
        *(u64*)&Hh[(size_t)cc * 20480] = __builtin_bit_cast(u64, o);
        const bf16x4 v = *(const bf16x4*)&Gh[(size_t)cc * 20480];
        #pragma unroll
        for (int j = 0; j < 4; ++j) acc[j] += bf2f(v[j]);
    }
}

// ---------------- Phase 3s: linear stage + frag-native state apply + final O ----------------
// grid 512 = (h = bid&7, c, qh), 256 thr (4 waves; wave w: queries qh*64+16w..+15).
// Hlds holds the chunk's Hb verbatim (fragment-native). Element (e,f) lives at
// byte 8*[(wfa*5+et)*64 + lsel*16 + (e&15)], wfa=f>>4, et=e>>4, lsel=(f&15)>>2.
// MFMA A-frag for lane (r,g), dt, ks: two b64 at (wfa*5+dt)*512 + (g&1)*256 + 8r, +128.
__global__ __launch_bounds__(256, 2)
void p3s_apply(const float* __restrict__ Qg, const __bf16* __restrict__ Hb,
               const __bf16* __restrict__ Op, const __bf16* __restrict__ Zp,
               float* __restrict__ Og)
{
    __shared__ __align__(128) unsigned char Hlds[40960];   // fragment-native (40KB)
    const int tid = threadIdx.x;
    const int lane = tid & 63;
    const int r = lane & 15, g = lane >> 4;
    const int w = tid >> 6;          // wave 0..3
    const int bid = blockIdx.x;
    const int h = bid & 7;
    const int x = bid >> 3;          // 0..63
    const int c = x >> 1;            // 0..31
    const int qh = x & 1;
    const int qb = c * CHUNK + qh * 64 + 16 * w;
    const int q = qb + r;

    // ---- prefetch Q row + bf16 partials (in flight during stage) ----
    float qr[16];
    {
        const float* qp = Qg + ((size_t)h * SEQN + q) * DKEY;
        #pragma unroll
        for (int m = 0; m < 4; ++m) {
            const f32x4 v = *(const f32x4*)(qp + 4 * m);
            qr[4 * m + 0] = v[0]; qr[4 * m + 1] = v[1];
            qr[4 * m + 2] = v[2]; qr[4 * m + 3] = v[3];
        }
    }
    bf16x4 opart[4];
    #pragma unroll
    for (int dt = 0; dt < 4; ++dt)
        opart[dt] = *(const bf16x4*)&Op[((size_t)h * SEQN + q) * DVAL + 16 * dt + 4 * g];
    const float zprev = bf2f(Zp[(size_t)h * SEQN + qb + r]);

    // ---- pure tid-linear streaming copy: Hb chunk -> LDS (no decode) ----
    {
        const unsigned char* src = (const unsigned char*)(Hb + (size_t)(h * NCHUNK + c) * 20480);
        #pragma unroll
        for (int k2 = 0; k2 < 10; ++k2) {
            const int off = 16 * (tid + 256 * k2);
            *(u64x2*)(Hlds + off) = *(const u64x2*)(src + off);
        }
    }
    __syncthreads();

    // ---- state apply: O_state = Psi(q) x H_{<c} ----
    float qsel[8];
    #pragma unroll
    for (int j = 0; j < 8; ++j) qsel[j] = (g & 1) ? qr[8 + j] : qr[j];
    f32x4 oacc[4] = {};
    f32x4 zacc4 = {};
    const int gsel = (g & 1) * 256 + 8 * r;   // lane's byte offset within a (wfa,et) panel
    #pragma unroll
    for (int ks = 0; ks < 8; ++ks) {
        const int wfa = 2 * ks + (g >> 1);
        const int pbase = wfa * 2560 + gsel;  // (wfa*5+0)*512 + gsel
        bf16x8 af[4];
        #pragma unroll
        for (int dt = 0; dt < 4; ++dt) {
            u64x2 both;
            both[0] = *(const u64*)(Hlds + pbase + dt * 512);
            both[1] = *(const u64*)(Hlds + pbase + dt * 512 + 128);
            af[dt] = __builtin_bit_cast(bf16x8, both);
        }
        u64x2 bz;
        bz[0] = *(const u64*)(Hlds + pbase + 4 * 512);
        bz[1] = *(const u64*)(Hlds + pbase + 4 * 512 + 128);
        const bf16x8 afz = __builtin_bit_cast(bf16x8, bz);

        const float qi = ALPHA * ((g & 2) ? qr[2 * ks + 1] : qr[2 * ks]);
        bf16x8 pf;
        #pragma unroll
        for (int j = 0; j < 8; ++j) pf[j] = (__bf16)(qi * qsel[j]);
        #pragma unroll
        for (int dt = 0; dt < 4; ++dt)
            oacc[dt] = __builtin_amdgcn_mfma_f32_16x16x32_bf16(af[dt], pf, oacc[dt], 0, 0, 0);
        zacc4 = __builtin_amdgcn_mfma_f32_16x16x32_bf16(afz, pf, zacc4, 0, 0, 0);
    }

    // ---- final stores: O = bf16 intra partial + state (Og write-once) ----
    #pragma unroll
    for (int dt = 0; dt < 4; ++dt) {
        f32x4 o;
        #pragma unroll
        for (int i = 0; i < 4; ++i) o[i] = bf2f(opart[dt][i]) + oacc[dt][i];
        *(f32x4*)(Og + ((size_t)h * SEQN + q) * DVAL + 16 * dt + 4 * g) = o;
    }
    if (lane < 16) {   // g==0 lanes: zacc4[0] holds the e=64 (ones) row for query r
        float* zp = Og + (size_t)NHEAD * SEQN * DVAL + (size_t)h * SEQN + qb;
        zp[r] = zprev + zacc4[0];
    }
}

// ---------------- Fallback (monolithic) if workspace too small ----------------
__global__ __launch_bounds__(128, 2)
void taylor_mono(const float* __restrict__ Qg, const float* __restrict__ Kg,
                 const float* __restrict__ Vg, float* __restrict__ Og)
{
    __shared__ __align__(16) __bf16 Kl[64 * 32];
    __shared__ __align__(16) __bf16 Vt[64 * 72];
    typedef __bf16 bf16x2 __attribute__((ext_vector_type(2)));
    const int tid = threadIdx.x;
    const int wv = tid >> 6;
    const int lane = tid & 63;
    const int r = lane & 15, g = lane >> 4;
    const int bid = blockIdx.x;
    const int h = bid & 7;
    const int tt = bid >> 3;
    const int qt = (tt & 1) ? (tt >> 1) : (63 - (tt >> 1));
    const int qb = qt * 64 + wv * 32;
    const float* __restrict__ Qh = Qg + (size_t)h * SEQN * DKEY;
    const float* __restrict__ Kh = Kg + (size_t)h * SEQN * DKEY;
    const float* __restrict__ Vh = Vg + (size_t)h * SEQN * DVAL;
    for (int row = tid; row < 64; row += 128) {
        bf16x8 z = {};
        *(bf16x8*)&Kl[row * 32 + 16] = z;
        *(bf16x8*)&Kl[row * 32 + 24] = z;
    }
    bf16x8 qfrag[2];
    #pragma unroll
    for (int uq = 0; uq < 2; ++uq) {
        bf16x8 f = {};
        if (g < 2) {
            const float* qp = Qh + (size_t)(qb + 16 * uq + r) * DKEY + 8 * g;
            const f32x4 a = *(const f32x4*)qp;
            const f32x4 b = *(const f32x4*)(qp + 4);
            #pragma unroll
            for (int j = 0; j < 4; ++j) { f[j] = (__bf16)a[j]; f[4 + j] = (__bf16)b[j]; }
        }
        qfrag[uq] = f;
    }
    f32x4 oacc[2][4] = {};
    float zacc0 = 0.f, zacc1 = 0.f;
    const int nkt = qt + 1;
    for (int kt = 0; kt < nkt; ++kt) {
        const int k0 = kt * 64;
        {
            const int key = tid >> 1, half = tid & 1;
            const float* kp = Kh + (size_t)(k0 + key) * DKEY + 8 * half;
            const f32x4 a = *(const f32x4*)kp;
            const f32x4 b = *(const f32x4*)(kp + 4);
            bf16x8 kb;
            #pragma unroll
            for (int j = 0; j < 4; ++j) { kb[j] = (__bf16)a[j]; kb[4 + j] = (__bf16)b[j]; }
            *(bf16x8*)&Kl[key * 32 + 8 * half] = kb;
        }
        {
            const int d = tid & 63;
            const int kp2 = (tid >> 6) * 2;
            #pragma unroll
            for (int i = 0; i < 16; ++i) {
                const int kk = i * 4 + kp2;
                const float a0 = Vh[(size_t)(k0 + kk) * DVAL + d];
                const float a1 = Vh[(size_t)(k0 + kk + 1) * DVAL + d];
                const int w32 = kk & 31;
                const int col = (kk & 32) + ((w32 >> 2) & 3) * 8 + ((w32 >> 4) << 2) + (kk & 3);
                bf16x2 p; p[0] = (__bf16)a0; p[1] = (__bf16)a1;
                *(bf16x2*)&Vt[d * 72 + col] = p;
            }
        }
        __syncthreads();
        const bool diag = (kt + 1 == nkt);
        #pragma unroll
        for (int ks = 0; ks < 2; ++ks) {
            if (k0 + 32 * ks < qb + 32) {
                bf16x8 vfrag[4];
                #pragma unroll
                for (int dt = 0; dt < 4; ++dt)
                    vfrag[dt] = *(const bf16x8*)&Vt[(16 * dt + r) * 72 + 32 * ks + 8 * g];
                bf16x8 kfr[2];
                #pragma unroll
                for (int uk = 0; uk < 2; ++uk)
                    kfr[uk] = *(const bf16x8*)&Kl[(32 * ks + 16 * uk + r) * 32 + 8 * g];
                const f32x4 zero4 = {};
                f32x4 s[2][2];
                #pragma unroll
                for (int uq = 0; uq < 2; ++uq)
                    #pragma unroll
                    for (int uk = 0; uk < 2; ++uk)
                        s[uq][uk] = __builtin_amdgcn_mfma_f32_16x16x32_bf16(
                            kfr[uk], qfrag[uq], zero4, 0, 0, 0);
                #pragma unroll
                for (int uq = 0; uq < 2; ++uq) {
                    bf16x8 pf;
                    float zs = 0.f;
                    #pragma unroll
                    for (int uk = 0; uk < 2; ++uk) {
                        const int kGb = k0 + 32 * ks + 16 * uk + 4 * g;
                        const int qG = qb + 16 * uq + r;
                        #pragma unroll
                        for (int i = 0; i < 4; ++i) {
                            const float sv = s[uq][uk][i];
                            float p = 0.03125f * sv * sv;
                            if (diag && (kGb + i > qG)) p = 0.f;
                            zs += p;
                            pf[4 * uk + i] = (__bf16)p;
                        }
                    }
                    if (uq == 0) zacc0 += zs; else zacc1 += zs;
                    #pragma unroll
                    for (int dt = 0; dt < 4; ++dt)
                        oacc[uq][dt] = __builtin_amdgcn_mfma_f32_16x16x32_bf16(
                            vfrag[dt], pf, oacc[uq][dt], 0, 0, 0);
                }
            }
        }
        __syncthreads();
    }
    #pragma unroll
    for (int uq = 0; uq < 2; ++uq) {
        const int q = qb + 16 * uq + r;
        #pragma unroll
        for (int dt = 0; dt < 4; ++dt) {
            float* op = Og + ((size_t)h * SEQN + q) * DVAL + 16 * dt + 4 * g;
            *(f32x4*)op = oacc[uq][dt];
        }
    }
    zacc0 += __shfl_xor(zacc0, 16); zacc0 += __shfl_xor(zacc0, 32);
    zacc1 += __shfl_xor(zacc1, 16); zacc1 += __shfl_xor(zacc1, 32);
    if (lane < 16) {
        float* zp = Og + (size_t)NHEAD * SEQN * DVAL + (size_t)h * SEQN + qb;
        zp[r] = zacc0;
        zp[16 + r] = zacc1;
    }
}

extern "C" void kernel_launch(void* const* d_in, const int* in_sizes, int n_in,
                              void* d_out, int out_size, void* d_ws, size_t ws_size,
                              hipStream_t stream) {
    const float* Q = (const float*)d_in[0];
    const float* K = (const float*)d_in[1];
    const float* V = (const float*)d_in[2];
    float* O = (float*)d_out;

    const size_t G_OFF  = 0;                       // 8*32*20480 bf16 = 10,485,760 B
    const size_t HB_OFF = 10485760;                // same size, fragment-native
    const size_t OP_OFF = 20971520;                // 8*4096*64 bf16 = 4,194,304 B
    const size_t ZP_OFF = 25165824;                // 8*4096 bf16 = 65,536 B
    const size_t NEED   = 25231360;

    if (ws_size >= NEED) {
        char* ws = (char*)d_ws;
        __bf16* G  = (__bf16*)(ws + G_OFF);
        __bf16* Hb = (__bf16*)(ws + HB_OFF);
        __bf16* Op = (__bf16*)(ws + OP_OFF);
        __bf16* Zp = (__bf16*)(ws + ZP_OFF);
        p01_state<<<dim3(256), dim3(512), 0, stream>>>(K, V, Q, G, Op, Zp);
        p2_scan  <<<dim3(160), dim3(256), 0, stream>>>(G, Hb);
        p3s_apply<<<dim3(512), dim3(256), 0, stream>>>(Q, Hb, Op, Zp, O);
    } else {
        taylor_mono<<<dim3(512), dim3(128), 0, stream>>>(Q, K, V, O);
    }
}